// Round 7
// baseline (1064.482 us; speedup 1.0000x reference)
//
#include <hip/hip_runtime.h>
#include <hip/hip_bf16.h>

#define A_N 100000
#define C_N 230
#define V_N 800
#define G_N 60

#define FLAG_RELU 2

#define SCAN_N   302080          // 295 * 1024 (padded row-count over 8 relations)
#define SCAN_NB  295
#define E_TOTAL  1804000

#define PCHUNK 16
#define LROW 392                 // LDS row stride (ushorts): 384 + 8 pad

typedef __attribute__((ext_vector_type(8))) short short8;
typedef __attribute__((ext_vector_type(4))) float f32x4;

__device__ __forceinline__ float bf16dec(unsigned short u){
  return __uint_as_float(((unsigned)u) << 16);
}
__device__ __forceinline__ unsigned short f2b(float v){
  union { __hip_bfloat16 h; unsigned short u; } c;
  c.h = __float2bfloat16(v);
  return c.u;
}
__device__ __forceinline__ float4 ldb4(const unsigned short* p){
  uint2 v = *(const uint2*)p;
  float4 r;
  r.x = __uint_as_float(v.x << 16);
  r.y = __uint_as_float(v.x & 0xffff0000u);
  r.z = __uint_as_float(v.y << 16);
  r.w = __uint_as_float(v.y & 0xffff0000u);
  return r;
}
static inline int imin(int a, int b){ return a < b ? a : b; }

// ---------------------------------------------------------------- detect dtype
__global__ void detect_dtype(const unsigned short* __restrict__ p, int* __restrict__ flag){
  __shared__ int bad;
  if (threadIdx.x == 0) bad = 0;
  __syncthreads();
  for (int i = threadIdx.x; i < 2048; i += blockDim.x){
    float v = fabsf(bf16dec(p[i]));
    if (!(v <= 1e6f)) atomicOr(&bad, 1);
  }
  __syncthreads();
  if (threadIdx.x == 0) *flag = bad;       // 1 => inputs stored as fp32
}

// ---------------------------------------------------------------- convert all
struct ConvTab { const void* src[29]; int dstoff[29]; int cum[30]; };

__global__ void convert_all(ConvTab tab, float* __restrict__ wsf,
                            const int* __restrict__ flagp, int total){
  const int f = *flagp;
  for (int idx = blockIdx.x*blockDim.x + threadIdx.x; idx < total;
       idx += gridDim.x*blockDim.x){
    int t = 0;
    while (idx >= tab.cum[t+1]) ++t;
    int l = idx - tab.cum[t];
    float v = f ? ((const float*)tab.src[t])[l]
                : bf16dec(((const unsigned short*)tab.src[t])[l]);
    wsf[tab.dstoff[t] + l] = v;
  }
}

// ---------------------------------------------------------------- prep combos (+ gat bias concat)
__global__ void prep_combos(const float* __restrict__ sWr, const float* __restrict__ sbl,
                            const float* __restrict__ gbias,
                            const float* __restrict__ gbl, const float* __restrict__ gbr,
                            float* __restrict__ wrcomb, float* __restrict__ sbcomb,
                            float* __restrict__ gbcomb,
                            float* __restrict__ gblx, float* __restrict__ gbrx){
  const int sets[4][3] = {{1,3,5},{0,-1,-1},{2,7,-1},{4,6,-1}};
  const float inv[4] = {1.f/3.f, 1.f, 0.5f, 0.5f};
  int idx = blockIdx.x*blockDim.x + threadIdx.x;
  if (idx >= 4*16384) return;
  int t = idx >> 14, j = idx & 16383;
  float s = 0.f;
  #pragma unroll
  for (int q = 0; q < 3; ++q){
    int k = sets[t][q];
    if (k >= 0) s += sWr[k*16384 + j];
  }
  wrcomb[idx] = s * inv[t];
  if (j < 128){
    float b1 = 0.f, b2 = 0.f;
    #pragma unroll
    for (int q = 0; q < 3; ++q){
      int k = sets[t][q];
      if (k >= 0){ b1 += sbl[k*128 + j]; b2 += gbias[k*128 + j]; }
    }
    sbcomb[t*128 + j] = b1 * inv[t];
    gbcomb[t*128 + j] = b2 * inv[t];
  }
  if (idx < 384){
    const int kl[3] = {0,2,4}, kr[3] = {1,3,5};
    int rel = idx >> 7, jj = idx & 127;
    gblx[idx] = gbl[kl[rel]*128 + jj];
    gbrx[idx] = gbr[kr[rel]*128 + jj];
  }
}

// ---------------------------------------------------------------- weight swizzle
struct SwzD { int src, dst, K, nkc, kc0, nt0; float scale; };
struct SwzTab { SwzD d[33]; int n, total; };

__global__ void swz_batch(const float* __restrict__ wsf, unsigned short* __restrict__ wsu,
                          SwzTab t){
  for (int idx = blockIdx.x*blockDim.x + threadIdx.x; idx < t.total;
       idx += gridDim.x*blockDim.x){
    int di = 0, local = idx;
    while (local >= t.d[di].K*128){ local -= t.d[di].K*128; ++di; }
    SwzD d = t.d[di];
    int j = local & 7, lane = (local>>3) & 63, rest = local >> 9;
    int kcn = d.K >> 5;
    int kc = rest % kcn, nt = rest / kcn;
    int k = kc*32 + (lane>>4)*8 + j;
    int n = nt*16 + (lane&15);
    float v = wsf[d.src + k*128 + n] * d.scale;
    wsu[(size_t)d.dst + ((size_t)((d.nt0+nt)*d.nkc + d.kc0+kc)*64 + lane)*8 + j] = f2b(v);
  }
}

// ---------------------------------------------------------------- CSR build (merged)
struct HTab {
  const int* dp[8];
  int E[8], cntoff[8], ndst[8], mode[8], bstart[9];
};

__global__ void hist_all(HTab t, int* __restrict__ cnt){
  __shared__ int l[800];
  int k = 0;
  while ((int)blockIdx.x >= t.bstart[k+1]) ++k;
  int lb = blockIdx.x - t.bstart[k], nb = t.bstart[k+1] - t.bstart[k];
  const int* dp = t.dp[k];
  int E = t.E[k];
  int* c = cnt + t.cntoff[k];
  if (t.mode[k]){
    int nd = t.ndst[k];
    for (int i = threadIdx.x; i < nd; i += blockDim.x) l[i] = 0;
    __syncthreads();
    for (int i = lb*blockDim.x + threadIdx.x; i < E; i += nb*blockDim.x)
      atomicAdd(&l[dp[i]], 1);
    __syncthreads();
    for (int i = threadIdx.x; i < nd; i += blockDim.x)
      if (l[i]) atomicAdd(&c[i], l[i]);
  } else {
    for (int i = lb*blockDim.x + threadIdx.x; i < E; i += nb*blockDim.x)
      atomicAdd(&c[dp[i]], 1);
  }
}

struct PTab {
  const int* sp[8]; const int* dp[8];
  int E[8], woffoff[8], ndst[8], mode[8], bstart[9];
};

__global__ void place_all(PTab t, int* __restrict__ woffb, int* __restrict__ csr){
  __shared__ int lcnt[800];
  __shared__ int lbase[800];
  int k = 0;
  while ((int)blockIdx.x >= t.bstart[k+1]) ++k;
  int lb = blockIdx.x - t.bstart[k], nb = t.bstart[k+1] - t.bstart[k];
  const int* sp = t.sp[k];
  const int* dp = t.dp[k];
  int E = t.E[k];
  int* woff = woffb + t.woffoff[k];
  const int tid = threadIdx.x;
  if (t.mode[k]){
    int nd = t.ndst[k];
    const int span = blockDim.x * PCHUNK;
    for (int b0 = lb*span; b0 < E; b0 += nb*span){
      for (int i = tid; i < nd; i += blockDim.x) lcnt[i] = 0;
      __syncthreads();
      int d[PCHUNK], s[PCHUNK], r[PCHUNK];
      #pragma unroll
      for (int j = 0; j < PCHUNK; ++j){
        int e = b0 + j*blockDim.x + tid;
        d[j] = -1;
        if (e < E){
          s[j] = sp[e];
          d[j] = dp[e];
          r[j] = atomicAdd(&lcnt[d[j]], 1);
        }
      }
      __syncthreads();
      for (int i = tid; i < nd; i += blockDim.x){
        int c = lcnt[i];
        if (c) lbase[i] = atomicAdd(&woff[i], c);
      }
      __syncthreads();
      #pragma unroll
      for (int j = 0; j < PCHUNK; ++j)
        if (d[j] >= 0) csr[lbase[d[j]] + r[j]] = s[j];
      __syncthreads();
    }
  } else {
    for (int i = lb*blockDim.x + tid; i < E; i += nb*blockDim.x){
      int pos = atomicAdd(&woff[dp[i]], 1);
      csr[pos] = sp[i];
    }
  }
}

__global__ void scan1(const int* __restrict__ cnt, int* __restrict__ rp, int* __restrict__ bsum){
  __shared__ int sd[256];
  int tid = threadIdx.x, blk = blockIdx.x;
  int base = blk*1024 + tid*4;
  int4 v = *(const int4*)(cnt + base);
  int s = v.x + v.y + v.z + v.w;
  sd[tid] = s;
  __syncthreads();
  for (int off = 1; off < 256; off <<= 1){
    int t = (tid >= off) ? sd[tid-off] : 0;
    __syncthreads();
    sd[tid] += t;
    __syncthreads();
  }
  int excl = sd[tid] - s;
  rp[base+0] = excl;
  rp[base+1] = excl + v.x;
  rp[base+2] = excl + v.x + v.y;
  rp[base+3] = excl + v.x + v.y + v.z;
  if (tid == 255) bsum[blk] = sd[255];
}

__global__ void scan2(int* __restrict__ bsum){
  __shared__ int sd[512];
  int tid = threadIdx.x;
  int v = (tid < SCAN_NB) ? bsum[tid] : 0;
  sd[tid] = v;
  __syncthreads();
  for (int off = 1; off < 512; off <<= 1){
    int t = (tid >= off) ? sd[tid-off] : 0;
    __syncthreads();
    sd[tid] += t;
    __syncthreads();
  }
  if (tid < SCAN_NB) bsum[tid] = sd[tid] - v;
}

__global__ void scan3(int* __restrict__ rp, int* __restrict__ woff,
                      const int* __restrict__ bsum){
  int idx = blockIdx.x*blockDim.x + threadIdx.x;
  if (idx >= SCAN_N) return;
  int v = rp[idx] + bsum[idx >> 10];
  rp[idx] = v;
  woff[idx] = v;
}

// ---------------------------------------------------------------- merged encoders
struct EncTab {
  int cum[5];
  int xoff[4], woff[4], boff[4], zoff[4], K[4];
};

__global__ void enc_batch(const float* __restrict__ wsf, unsigned short* __restrict__ wsu,
                          EncTab t){
  for (int idx = blockIdx.x*blockDim.x + threadIdx.x; idx < t.cum[4];
       idx += gridDim.x*blockDim.x){
    int s = 0;
    while (idx >= t.cum[s+1]) ++s;
    int local = idx - t.cum[s];
    if (s < 3){
      int r = local >> 7, c = local & 127;
      int K = t.K[s];
      float acc = wsf[t.boff[s] + c];
      for (int k = 0; k < K; ++k)
        acc = fmaf(wsf[t.xoff[s] + r*K + k], wsf[t.woff[s] + (k<<7) + c], acc);
      wsu[(size_t)t.zoff[s] + (size_t)r*128 + c] = f2b(fmaxf(acc, 0.f));
    } else {
      wsu[(size_t)t.zoff[3] + local] = f2b(wsf[t.xoff[3] + local]);
    }
  }
}

// ---------------------------------------------------------------- MFMA GEMM
__device__ __forceinline__ void mfma_core(
    const unsigned short* __restrict__ wsu, const float* __restrict__ wsf,
    int xoff, int xstride, int x2off, int x2stride, int kcsplit,
    int woff, int nkc, int biasoff, int yoff, int ystride,
    int M, int flags, int mblk, int nblk)
{
  int tid = threadIdx.x;
  int wv = tid >> 6, lane = tid & 63;
  int quad = lane >> 4, ml = lane & 15;
  int m0 = mblk*64 + wv*16;
  if (m0 >= M) return;
  int arow = m0 + ml;
  bool rowok = arow < M;
  f32x4 acc[8];
  #pragma unroll
  for (int i = 0; i < 8; ++i) acc[i] = (f32x4){0.f, 0.f, 0.f, 0.f};
  for (int kc = 0; kc < nkc; ++kc){
    short8 a = (short8){0,0,0,0,0,0,0,0};
    if (rowok){
      size_t ao = (kc < kcsplit)
        ? (size_t)xoff  + (size_t)arow*xstride  + kc*32 + quad*8
        : (size_t)x2off + (size_t)arow*x2stride + (kc - kcsplit)*32 + quad*8;
      a = *(const short8*)(wsu + ao);
    }
    size_t wbase = (size_t)woff + ((size_t)(nblk*8)*nkc + kc)*512 + lane*8;
    #pragma unroll
    for (int nt = 0; nt < 8; ++nt){
      short8 b = *(const short8*)(wsu + wbase + (size_t)nt*nkc*512);
      acc[nt] = __builtin_amdgcn_mfma_f32_16x16x32_bf16(a, b, acc[nt], 0, 0, 0);
    }
  }
  #pragma unroll
  for (int nt = 0; nt < 8; ++nt){
    int col = nblk*128 + nt*16 + ml;
    float bv = (biasoff >= 0) ? wsf[biasoff + col] : 0.f;
    #pragma unroll
    for (int r = 0; r < 4; ++r){
      int orow = m0 + quad*4 + r;
      if (orow < M){
        float v = acc[nt][r] + bv;
        if (flags & FLAG_RELU) v = fmaxf(v, 0.f);
        *((unsigned short*)wsu + (size_t)yoff + (size_t)orow*ystride + col) = f2b(v);
      }
    }
  }
}

struct GB2 { int xoff, xstride, x2off, x2stride, kcsplit, woff, nkc, biasoff,
             yoff, ystride, M, flags, nblk; };
struct GB2Tab { GB2 d[13]; int b0[14]; int n; };

__global__ __launch_bounds__(256) void mfma_gemm_b2(void* ws, GB2Tab t){
  int b = blockIdx.x, di = 0;
  while (b >= t.b0[di+1]) ++di;
  GB2 g = t.d[di];
  mfma_core((const unsigned short*)ws, (const float*)ws, g.xoff, g.xstride,
            g.x2off, g.x2stride, g.kcsplit, g.woff, g.nkc, g.biasoff,
            g.yoff, g.ystride, g.M, g.flags, b - t.b0[di], g.nblk);
}

// ---------------------------------------------------------------- SAGE small gathers
struct SgD { int src, sstr, rpoff, aggoff, nd, nc; };
struct SgTab { SgD d[5]; int cumw[6]; };

__global__ void sage_small(const unsigned short* __restrict__ wsu, float* __restrict__ wsf,
    const int* __restrict__ csr, const int* __restrict__ rpb, SgTab t)
{
  int gid = (blockIdx.x*blockDim.x + threadIdx.x) >> 6;
  if (gid >= t.cumw[5]) return;
  int lane = threadIdx.x & 63;
  int half = lane >> 5, sub = lane & 31, f = sub*4;
  int di = 0;
  while (gid >= t.cumw[di+1]) ++di;
  SgD d = t.d[di];
  int local = gid - t.cumw[di];
  int row = local / d.nc, c = local - row*d.nc;
  const unsigned short* base = wsu + (size_t)d.src + f;
  int st = rpb[d.rpoff + row], en = rpb[d.rpoff + row + 1];
  float4 acc = {0.f, 0.f, 0.f, 0.f};
  int i = st + c + half*d.nc;
  int step = 2*d.nc;
  for (; i + step < en; i += 2*step){
    int s0 = csr[i], s1 = csr[i+step];
    float4 v0 = ldb4(base + (size_t)s0*d.sstr);
    float4 v1 = ldb4(base + (size_t)s1*d.sstr);
    acc.x += v0.x + v1.x; acc.y += v0.y + v1.y;
    acc.z += v0.z + v1.z; acc.w += v0.w + v1.w;
  }
  if (i < en){
    float4 v0 = ldb4(base + (size_t)csr[i]*d.sstr);
    acc.x += v0.x; acc.y += v0.y; acc.z += v0.z; acc.w += v0.w;
  }
  acc.x += __shfl_xor(acc.x, 32); acc.y += __shfl_xor(acc.y, 32);
  acc.z += __shfl_xor(acc.z, 32); acc.w += __shfl_xor(acc.w, 32);
  if (half == 0){
    float* o = wsf + (size_t)d.aggoff + (size_t)row*128 + f;
    atomicAdd(o,   acc.x); atomicAdd(o+1, acc.y);
    atomicAdd(o+2, acc.z); atomicAdd(o+3, acc.w);
  }
}

struct AfD { int aggoff, rpoff, dstu, dstr, nd; };
struct AfTab { AfD d[5]; int n; };

__global__ void aggfin_batch(unsigned short* __restrict__ wsu, const float* __restrict__ wsf,
                             const int* __restrict__ rpb, AfTab t, int total){
  int idx = blockIdx.x*blockDim.x + threadIdx.x;
  if (idx >= total) return;
  int di = 0, local = idx;
  while (local >= t.d[di].nd*128){ local -= t.d[di].nd*128; ++di; }
  AfD d = t.d[di];
  int row = local >> 7, col = local & 127;
  int deg = rpb[d.rpoff + row + 1] - rpb[d.rpoff + row];
  float sc = 1.f / (float)(deg > 1 ? deg : 1);
  wsu[(size_t)d.dstu + (size_t)row*d.dstr + col] = f2b(wsf[(size_t)d.aggoff + local] * sc);
}

// ---------------------------------------------------------------- SAGE athlete fused
// Block = 64 athlete rows. Phase 1: gather 3 rel-means into LDS [64][LROW] bf16.
// Phase 2: K=512 MFMA (kc0-3 from hA global, kc4-15 from LDS) -> yA.
__global__ __launch_bounds__(256) void sage_ath_fused(
    unsigned short* __restrict__ wsu, const float* __restrict__ wsf,
    const int* __restrict__ csr, const int* __restrict__ rpb,
    int uhC, int uhE, int uhG, int rp1, int rp3, int rp5,
    int uhA, int woff, int biasoff, int yoff)
{
  __shared__ unsigned short lds[64*LROW];
  int tid = threadIdx.x;
  int wv = tid >> 6, lane = tid & 63;
  int half = lane >> 5, sub = lane & 31, f = sub*4;
  int m0 = blockIdx.x*64;
  int srcs[3] = {uhC, uhE, uhG};
  int sstr[3] = {256, 384, 384};
  int rps[3]  = {rp1, rp3, rp5};
  for (int r = 0; r < 16; ++r){
    int row = m0 + wv*16 + r;
    if (row >= A_N) break;
    #pragma unroll
    for (int rel = 0; rel < 3; ++rel){
      const unsigned short* base = wsu + (size_t)srcs[rel] + f;
      int str = sstr[rel];
      int st = rpb[rps[rel] + row], en = rpb[rps[rel] + row + 1];
      float4 acc = {0.f, 0.f, 0.f, 0.f};
      int i = st + half;
      for (; i + 2 < en; i += 4){
        int s0 = csr[i], s1 = csr[i+2];
        float4 v0 = ldb4(base + (size_t)s0*str);
        float4 v1 = ldb4(base + (size_t)s1*str);
        acc.x += v0.x + v1.x; acc.y += v0.y + v1.y;
        acc.z += v0.z + v1.z; acc.w += v0.w + v1.w;
      }
      if (i < en){
        float4 v0 = ldb4(base + (size_t)csr[i]*str);
        acc.x += v0.x; acc.y += v0.y; acc.z += v0.z; acc.w += v0.w;
      }
      acc.x += __shfl_xor(acc.x, 32); acc.y += __shfl_xor(acc.y, 32);
      acc.z += __shfl_xor(acc.z, 32); acc.w += __shfl_xor(acc.w, 32);
      if (half == 0){
        int deg = en - st;
        float sc = 1.f / (float)(deg > 1 ? deg : 1);
        ushort4 o;
        o.x = f2b(acc.x*sc); o.y = f2b(acc.y*sc);
        o.z = f2b(acc.z*sc); o.w = f2b(acc.w*sc);
        *(ushort4*)&lds[(wv*16 + r)*LROW + rel*128 + f] = o;
      }
    }
  }
  __syncthreads();
  int quad = lane >> 4, ml = lane & 15;
  if (m0 + wv*16 >= A_N) return;
  int arow = m0 + wv*16 + ml;
  bool rowok = arow < A_N;
  f32x4 acc[8];
  #pragma unroll
  for (int i = 0; i < 8; ++i) acc[i] = (f32x4){0.f, 0.f, 0.f, 0.f};
  for (int kc = 0; kc < 16; ++kc){
    short8 a = (short8){0,0,0,0,0,0,0,0};
    if (rowok){
      if (kc < 4) a = *(const short8*)(wsu + (size_t)uhA + (size_t)arow*128 + kc*32 + quad*8);
      else        a = *(const short8*)&lds[(wv*16 + ml)*LROW + (kc-4)*32 + quad*8];
    }
    size_t wbase = (size_t)woff + (size_t)kc*512 + lane*8;
    #pragma unroll
    for (int nt = 0; nt < 8; ++nt){
      short8 b = *(const short8*)(wsu + wbase + (size_t)nt*16*512);
      acc[nt] = __builtin_amdgcn_mfma_f32_16x16x32_bf16(a, b, acc[nt], 0, 0, 0);
    }
  }
  #pragma unroll
  for (int nt = 0; nt < 8; ++nt){
    int col = nt*16 + ml;
    float bv = wsf[biasoff + col];
    #pragma unroll
    for (int r = 0; r < 4; ++r){
      int orow = m0 + wv*16 + quad*4 + r;
      if (orow < A_N)
        wsu[(size_t)yoff + (size_t)orow*128 + col] = f2b(fmaxf(acc[nt][r] + bv, 0.f));
    }
  }
}

// ---------------------------------------------------------------- GATv2 macros
#define GAT_LOGIT(xv, pout)                                                \
  {                                                                        \
    float e0 = (xv).x + xrv.x, e1 = (xv).y + xrv.y;                        \
    float e2 = (xv).z + xrv.z, e3 = (xv).w + xrv.w;                        \
    e0 = e0 > 0.f ? e0 : 0.2f*e0; e1 = e1 > 0.f ? e1 : 0.2f*e1;            \
    e2 = e2 > 0.f ? e2 : 0.2f*e2; e3 = e3 > 0.f ? e3 : 0.2f*e3;            \
    pout = e0*av.x + e1*av.y + e2*av.z + e3*av.w;                          \
    pout += __shfl_xor(pout, 1); pout += __shfl_xor(pout, 2);              \
    pout += __shfl_xor(pout, 4);                                           \
  }

#define GAT_UPD(xv)                                                        \
  {                                                                        \
    float p;                                                               \
    GAT_LOGIT(xv, p);                                                      \
    float nm = fmaxf(m, p);                                                \
    float scw = __expf(m - nm);                                            \
    float pe = __expf(p - nm);                                             \
    l = l*scw + pe;                                                        \
    acc.x = acc.x*scw + pe*(xv).x; acc.y = acc.y*scw + pe*(xv).y;          \
    acc.z = acc.z*scw + pe*(xv).z; acc.w = acc.w*scw + pe*(xv).w;          \
    m = nm;                                                                \
  }

#define GAT_UPD2(x0, x1)                                                   \
  {                                                                        \
    float p0, p1;                                                          \
    GAT_LOGIT(x0, p0);                                                     \
    GAT_LOGIT(x1, p1);                                                     \
    float nm = fmaxf(m, fmaxf(p0, p1));                                    \
    float scw = __expf(m - nm);                                            \
    float pe0 = __expf(p0 - nm);                                           \
    float pe1 = __expf(p1 - nm);                                           \
    l = l*scw + pe0 + pe1;                                                 \
    acc.x = acc.x*scw + pe0*(x0).x + pe1*(x1).x;                           \
    acc.y = acc.y*scw + pe0*(x0).y + pe1*(x1).y;                           \
    acc.z = acc.z*scw + pe0*(x0).z + pe1*(x1).z;                           \
    acc.w = acc.w*scw + pe0*(x0).w + pe1*(x1).w;                           \
    m = nm;                                                                \
  }

#define GAT_MERGE_HALVES                                                   \
  {                                                                        \
    float mo = __shfl_xor(m, 32);                                          \
    float lo = __shfl_xor(l, 32);                                          \
    float4 ao;                                                             \
    ao.x = __shfl_xor(acc.x, 32); ao.y = __shfl_xor(acc.y, 32);            \
    ao.z = __shfl_xor(acc.z, 32); ao.w = __shfl_xor(acc.w, 32);            \
    float nm = fmaxf(m, mo);                                               \
    float w  = (m  == -INFINITY) ? 0.f : __expf(m  - nm);                  \
    float wo = (mo == -INFINITY) ? 0.f : __expf(mo - nm);                  \
    l = l*w + lo*wo;                                                       \
    acc.x = acc.x*w + ao.x*wo; acc.y = acc.y*w + ao.y*wo;                  \
    acc.z = acc.z*w + ao.z*wo; acc.w = acc.w*w + ao.w*wo;                  \
    m = nm;                                                                \
  }

// ---------------------------------------------------------------- GAT athlete fused
// Block = 64 athlete rows. Phase 1: gxr = yA @ gWrX + gbrx -> LDS [64][LROW] bf16.
// Phase 2: 3-relation online-softmax attention (xrv from LDS) -> outA.
__global__ __launch_bounds__(256) void gat_ath_fused(
    unsigned short* __restrict__ wsu, const float* __restrict__ wsf,
    const int* __restrict__ csr, const int* __restrict__ rpb,
    int uyA, int woff, int biasoff,
    int uxl1, int uxl3, int uxl5, int oatt, int rp1, int rp3, int rp5, int uout)
{
  __shared__ unsigned short lds[64*LROW];
  int tid = threadIdx.x;
  int wv = tid >> 6, lane = tid & 63;
  int quad = lane >> 4, ml = lane & 15;
  int m0 = blockIdx.x*64;
  {
    int arow = m0 + wv*16 + ml;
    bool rowok = arow < A_N;
    for (int nb = 0; nb < 3; ++nb){
      f32x4 acc[8];
      #pragma unroll
      for (int i = 0; i < 8; ++i) acc[i] = (f32x4){0.f, 0.f, 0.f, 0.f};
      for (int kc = 0; kc < 4; ++kc){
        short8 a = (short8){0,0,0,0,0,0,0,0};
        if (rowok) a = *(const short8*)(wsu + (size_t)uyA + (size_t)arow*128 + kc*32 + quad*8);
        size_t wbase = (size_t)woff + ((size_t)(nb*8)*4 + kc)*512 + lane*8;
        #pragma unroll
        for (int nt = 0; nt < 8; ++nt){
          short8 b = *(const short8*)(wsu + wbase + (size_t)nt*4*512);
          acc[nt] = __builtin_amdgcn_mfma_f32_16x16x32_bf16(a, b, acc[nt], 0, 0, 0);
        }
      }
      #pragma unroll
      for (int nt = 0; nt < 8; ++nt){
        int col = nb*128 + nt*16 + ml;
        float bv = wsf[biasoff + col];
        #pragma unroll
        for (int r = 0; r < 4; ++r){
          int lrow = wv*16 + quad*4 + r;
          lds[lrow*LROW + col] = f2b(acc[nt][r] + bv);
        }
      }
    }
  }
  __syncthreads();
  int half = lane >> 5, sub = lane & 31, f = sub*4;
  int xls[3] = {uxl1, uxl3, uxl5};
  int rps[3] = {rp1, rp3, rp5};
  const int attk[3] = {1, 3, 5};
  for (int r = 0; r < 16; ++r){
    int row = m0 + wv*16 + r;
    if (row >= A_N) break;
    float4 oacc = {0.f, 0.f, 0.f, 0.f};
    #pragma unroll
    for (int rel = 0; rel < 3; ++rel){
      float4 xrv = ldb4(&lds[(wv*16 + r)*LROW + rel*128 + f]);
      float4 av  = *(const float4*)(wsf + oatt + attk[rel]*128 + f);
      const unsigned short* base = wsu + (size_t)xls[rel] + f;
      int st = rpb[rps[rel] + row], en = rpb[rps[rel] + row + 1];
      float m = -INFINITY, l = 0.f;
      float4 acc = {0.f, 0.f, 0.f, 0.f};
      int i = st + half;
      for (; i + 2 < en; i += 4){
        int s0 = csr[i], s1 = csr[i+2];
        float4 x0 = ldb4(base + (size_t)s0*128);
        float4 x1 = ldb4(base + (size_t)s1*128);
        GAT_UPD2(x0, x1);
      }
      if (i < en){
        float4 x0 = ldb4(base + (size_t)csr[i]*128);
        GAT_UPD(x0);
      }
      GAT_MERGE_HALVES;
      float inv = 1.f / (l + 1e-16f);
      oacc.x += acc.x * inv; oacc.y += acc.y * inv;
      oacc.z += acc.z * inv; oacc.w += acc.w * inv;
    }
    if (half == 0){
      ushort4 o;
      o.x = f2b(oacc.x * (1.f/3.f)); o.y = f2b(oacc.y * (1.f/3.f));
      o.z = f2b(oacc.z * (1.f/3.f)); o.w = f2b(oacc.w * (1.f/3.f));
      *(ushort4*)((unsigned short*)wsu + (size_t)uout + (size_t)row*128 + f) = o;
    }
  }
}

// small-dst relations (k=0,2,4,6,7) -> partials
struct GoD { int xl, xlstr, xr, attoff, rpoff, prefix, nd, nc; };
struct GoTab { GoD d[5]; int cumw[6]; };

__global__ void gat_online_batch(const unsigned short* __restrict__ wsu,
    const float* __restrict__ wsf, const int* __restrict__ csr,
    const int* __restrict__ rpb, float* __restrict__ part, GoTab t)
{
  int gid = (blockIdx.x*blockDim.x + threadIdx.x) >> 6;
  if (gid >= t.cumw[5]) return;
  int di = 0;
  while (gid >= t.cumw[di+1]) ++di;
  GoD d = t.d[di];
  int local = gid - t.cumw[di];
  int row = local / d.nc, c = local - row*d.nc;
  int lane = threadIdx.x & 63;
  int half = lane >> 5, sub = lane & 31, f = sub*4, h = sub >> 3;
  float4 xrv = ldb4(wsu + (size_t)d.xr + (size_t)row*128 + f);
  float4 av  = *(const float4*)(wsf + d.attoff + f);
  const unsigned short* base = wsu + (size_t)d.xl + f;
  int st = rpb[d.rpoff + row], en = rpb[d.rpoff + row + 1];
  float m = -INFINITY, l = 0.f;
  float4 acc = {0.f, 0.f, 0.f, 0.f};
  int i = st + c + half*d.nc;
  int step = 2*d.nc;
  for (; i + step < en; i += 2*step){
    int s0 = csr[i], s1 = csr[i+step];
    float4 x0 = ldb4(base + (size_t)s0*d.xlstr);
    float4 x1 = ldb4(base + (size_t)s1*d.xlstr);
    GAT_UPD2(x0, x1);
  }
  if (i < en){
    float4 x0 = ldb4(base + (size_t)csr[i]*d.xlstr);
    GAT_UPD(x0);
  }
  GAT_MERGE_HALVES;
  if (half == 0){
    float* pr = part + (size_t)(d.prefix + local)*136;
    if ((sub & 7) == 0){ pr[h] = m; pr[4+h] = l; }
    *(float4*)(pr + 8 + f) = acc;
  }
}

struct MgD { int prefix, outoff, nd, nc; float invS; };
struct MgTab { MgD d[5]; int cumw[6]; };

__global__ void gat_merge_batch(const float* __restrict__ part, float* __restrict__ wsf,
                                MgTab t){
  int gid = (blockIdx.x*blockDim.x + threadIdx.x) >> 6;
  if (gid >= t.cumw[5]) return;
  int di = 0;
  while (gid >= t.cumw[di+1]) ++di;
  MgD d = t.d[di];
  int row = gid - t.cumw[di];
  int lane = threadIdx.x & 63, f = lane*2, h = lane >> 4;
  float M = -INFINITY;
  for (int c = 0; c < d.nc; ++c)
    M = fmaxf(M, part[(size_t)(d.prefix + row*d.nc + c)*136 + h]);
  float L = 0.f;
  float2 acc = {0.f, 0.f};
  for (int c = 0; c < d.nc; ++c){
    const float* pr = part + (size_t)(d.prefix + row*d.nc + c)*136;
    float mc = pr[h];
    float w = (mc == -INFINITY) ? 0.f : __expf(mc - M);
    L += pr[4+h] * w;
    acc.x += pr[8+f]   * w;
    acc.y += pr[8+f+1] * w;
  }
  float inv = d.invS / (L + 1e-16f);
  float* o = wsf + (size_t)d.outoff + (size_t)row*128 + f;
  o[0] = acc.x * inv;
  o[1] = acc.y * inv;
}

// ---------------------------------------------------------------- final output
__global__ void final_out(const unsigned short* __restrict__ wsu,
  const float* __restrict__ wsf, int uoutA, int oC0, int oE2, int oE7, int oG4, int oG6,
  int ogb, const int* __restrict__ flagp, void* __restrict__ dout)
{
  const int fl = *flagp;
  int idx = blockIdx.x*blockDim.x + threadIdx.x;
  const int total = 101090*128;
  if (idx >= total) return;
  int row = idx >> 7, c = idx & 127;
  float v; int t;
  if (row < A_N){ v = bf16dec(wsu[(size_t)uoutA + idx]); t = 0; }
  else if (row < A_N + C_N){ v = wsf[oC0 + (row - A_N)*128 + c]; t = 1; }
  else if (row < A_N + C_N + V_N){
    int l = (row - A_N - C_N)*128 + c;
    v = wsf[oE2 + l] + wsf[oE7 + l]; t = 2;
  } else {
    int l = (row - A_N - C_N - V_N)*128 + c;
    v = wsf[oG4 + l] + wsf[oG6 + l]; t = 3;
  }
  v += wsf[ogb + t*128 + c];
  if (fl) ((float*)dout)[idx] = v;
  else    ((__hip_bfloat16*)dout)[idx] = __float2bfloat16(v);
}

__global__ void ws_fail(float* __restrict__ out, float mb){
  if (threadIdx.x == 0 && blockIdx.x == 0) out[0] = mb;
}

// ================================================================ host
extern "C" void kernel_launch(void* const* d_in, const int* in_sizes, int n_in,
                              void* d_out, int out_size, void* d_ws, size_t ws_size,
                              hipStream_t stream)
{
  float* wsf = (float*)d_ws;
  unsigned short* wsu = (unsigned short*)d_ws;
  int* flagp = (int*)d_ws;
  size_t off = 16;
  auto alloc = [&](size_t n){ size_t o = off; off += (n + 15) & ~(size_t)15; return (int)o; };
  auto allocU = [&](size_t nu){ return 2*alloc((nu + 1)/2); };  // returns ushort offset

  static const int conv_in_idx[29] = {0,1,2,3, 8,9,10,11, 12,13,14,15, 16,17,18,19,
                                      20,21,22,23, 24,25,26, 27,28,29,30,31,32};
  static const int conv_n[29] = {700000,690,307200,120,
                                 896,128,16384,128, 384,128,16384,128,
                                 49152,128,16384,128, 256,128,16384,128,
                                 131072,1024,131072, 131072,1024,131072,1024,1024,1024};
  ConvTab tab;
  int coff[29];
  int total = 0;
  for (int i = 0; i < 29; ++i){
    tab.src[i] = d_in[conv_in_idx[i]];
    coff[i] = alloc((size_t)conv_n[i]);
    tab.dstoff[i] = coff[i];
    tab.cum[i] = total; total += conv_n[i];
  }
  tab.cum[29] = total;

  const int o_sWl = coff[20], o_sbl = coff[21];
  const int o_gWl = coff[23], o_gbl = coff[24], o_gWr = coff[25], o_gbr = coff[26];
  const int o_gatt = coff[27], o_gbias = coff[28];

  int o_wrcomb = alloc(4*16384);
  int o_sbcomb = alloc(512);
  int o_gbcomb = alloc(512);
  int o_gblx = alloc(384);
  int o_gbrx = alloc(384);
  int o_cnt  = alloc(SCAN_N);
  int o_rp   = alloc(SCAN_N);
  int o_woff = alloc(SCAN_N);
  int o_bsum = alloc(1024);
  int o_csr  = alloc(E_TOTAL);
  int o_part = alloc((size_t)36160*136);
  int o_aggS = alloc((size_t)1950*128);           // 5 buffers: 230,800,800,60,60 rows
  int o_outC0 = alloc(230*128);
  int o_outE2 = alloc(800*128);
  int o_outE7 = alloc(800*128);
  int o_outG4 = alloc(60*128);
  int o_outG6 = alloc(60*128);

  // bf16 buffers (ushort offsets)
  int u_bswz = allocU(573440);
  int u_xEb  = allocU(307200);
  int u_zC   = allocU(230*128);
  int u_zE   = allocU(800*128);
  int u_zG   = allocU(60*128);
  int u_sxC  = allocU(230*256);
  int u_sxE  = allocU(800*384);
  int u_sxG  = allocU(60*384);
  int u_yC   = allocU(230*128);
  int u_yE   = allocU(800*128);
  int u_yG   = allocU(60*128);
  int u_xl1  = allocU(230*128);
  int u_xl3  = allocU(800*128);
  int u_xl5  = allocU(60*128);
  int u_xl6  = allocU(800*128);
  int u_xl7  = allocU(60*128);
  int u_xr0  = allocU(230*128);
  int u_xr2  = allocU(800*128);
  int u_xr4  = allocU(60*128);
  int u_xr6  = allocU(60*128);
  int u_xr7  = allocU(800*128);
  int u_big0 = allocU((size_t)A_N*128);   // zA, then yA
  int u_bigH = allocU((size_t)A_N*128);   // hA, then outA
  int u_bigA = allocU((size_t)A_N*384);   // gxl

  if (off*4 > ws_size){
    ws_fail<<<1, 64, 0, stream>>>((float*)d_out, (float)((off*4) >> 20));
    return;
  }

  // swizzled-weight sub-offsets (within bswz)
  const int u_eAW2 = u_bswz + 0,      u_eCW2 = u_bswz + 16384;
  const int u_eEW2 = u_bswz + 32768,  u_eGW2 = u_bswz + 49152;
  const int u_eEW1 = u_bswz + 65536;
  const int u_sxAW = u_bswz + 114688, u_sxCW = u_bswz + 180224;
  const int u_sxEW = u_bswz + 212992, u_sxGW = u_bswz + 262144;
  const int u_gxlW = u_bswz + 311296, u_gxrW = u_bswz + 360448;
  int u_smW[10];
  for (int i = 0; i < 10; ++i) u_smW[i] = u_bswz + 409600 + i*16384;

  const int n_nodes[4] = {A_N, C_N, V_N, G_N};
  const int et_dst[8] = {1,0,2,0,3,0,3,2};
  const int et_ei[8]  = {4,4,5,5,6,6,7,7};
  const int et_rev[8] = {0,1,0,1,0,1,0,1};
  const int et_E[8]   = {100000,100000,500000,500000,300000,300000,2000,2000};

  const int* esp[8]; const int* edp[8]; int rowbase[8];
  {
    int rb = 0;
    for (int k = 0; k < 8; ++k){
      const int* ei = (const int*)d_in[et_ei[k]];
      int E = et_E[k];
      esp[k] = ei + (et_rev[k] ? E : 0);
      edp[k] = ei + (et_rev[k] ? 0 : E);
      rowbase[k] = rb; rb += n_nodes[et_dst[k]];
    }
  }
  int* rpb_p  = (int*)(wsf + o_rp);
  int* csr_p  = (int*)(wsf + o_csr);

  // ---------------- conversions / weight prep
  detect_dtype<<<1, 256, 0, stream>>>((const unsigned short*)d_in[2], flagp);
  convert_all<<<2048, 256, 0, stream>>>(tab, wsf, flagp, total);
  prep_combos<<<(4*16384 + 255)/256, 256, 0, stream>>>(wsf + coff[22], wsf + o_sbl,
      wsf + o_gbias, wsf + o_gbl, wsf + o_gbr,
      wsf + o_wrcomb, wsf + o_sbcomb, wsf + o_gbcomb, wsf + o_gblx, wsf + o_gbrx);

  SwzTab st; int sn = 0, stotal = 0;
  auto push = [&](int src, int K, int dst, int nkc, int kc0, int nt0, float sc){
    st.d[sn++] = SwzD{src, dst, K, nkc, kc0, nt0, sc};
    stotal += K*128;
  };
  push(coff[6],  128, u_eAW2, 4, 0, 0, 1.f);
  push(coff[10], 128, u_eCW2, 4, 0, 0, 1.f);
  push(coff[14], 128, u_eEW2, 4, 0, 0, 1.f);
  push(coff[18], 128, u_eGW2, 4, 0, 0, 1.f);
  push(coff[12], 384, u_eEW1, 12, 0, 0, 1.f);
  push(o_wrcomb + 0,     128, u_sxAW, 16, 0,  0, 1.f);
  push(o_sWl + 1*16384,  128, u_sxAW, 16, 4,  0, 1.f/3.f);
  push(o_sWl + 3*16384,  128, u_sxAW, 16, 8,  0, 1.f/3.f);
  push(o_sWl + 5*16384,  128, u_sxAW, 16, 12, 0, 1.f/3.f);
  push(o_wrcomb + 16384, 128, u_sxCW, 8, 0, 0, 1.f);
  push(o_sWl + 0*16384,  128, u_sxCW, 8, 4, 0, 1.f);
  push(o_wrcomb + 32768, 128, u_sxEW, 12, 0, 0, 1.f);
  push(o_sWl + 2*16384,  128, u_sxEW, 12, 4, 0, 0.5f);
  push(o_sWl + 7*16384,  128, u_sxEW, 12, 8, 0, 0.5f);
  push(o_wrcomb + 49152, 128, u_sxGW, 12, 0, 0, 1.f);
  push(o_sWl + 4*16384,  128, u_sxGW, 12, 4, 0, 0.5f);
  push(o_sWl + 6*16384,  128, u_sxGW, 12, 8, 0, 0.5f);
  push(o_gWl + 0*16384, 128, u_gxlW, 4, 0, 0,  1.f);
  push(o_gWl + 2*16384, 128, u_gxlW, 4, 0, 8,  1.f);
  push(o_gWl + 4*16384, 128, u_gxlW, 4, 0, 16, 1.f);
  push(o_gWr + 1*16384, 128, u_gxrW, 4, 0, 0,  1.f);
  push(o_gWr + 3*16384, 128, u_gxrW, 4, 0, 8,  1.f);
  push(o_gWr + 5*16384, 128, u_gxrW, 4, 0, 16, 1.f);
  const int xlk[5] = {1,3,5,6,7};
  for (int i = 0; i < 5; ++i) push(o_gWl + xlk[i]*16384, 128, u_smW[i], 4, 0, 0, 1.f);
  const int xrk[5] = {0,2,4,6,7};
  for (int i = 0; i < 5; ++i) push(o_gWr + xrk[i]*16384, 128, u_smW[5+i], 4, 0, 0, 1.f);
  st.n = sn; st.total = stotal;
  swz_batch<<<(stotal + 255)/256, 256, 0, stream>>>(wsf, wsu, st);

  // ---------------- CSR build (merged hist / place)
  hipMemsetAsync(wsf + o_cnt, 0, (size_t)SCAN_N*4, stream);
  {
    HTab ht; PTab pt;
    int hb = 0, pb = 0;
    for (int k = 0; k < 8; ++k){
      int E = et_E[k], nd = n_nodes[et_dst[k]];
      int small = (nd <= 800);
      ht.dp[k] = edp[k]; ht.E[k] = E; ht.cntoff[k] = rowbase[k];
      ht.ndst[k] = nd; ht.mode[k] = small;
      ht.bstart[k] = hb;
      hb += small ? imin(128, (E + 255)/256) : (E + 255)/256;
      pt.sp[k] = esp[k]; pt.dp[k] = edp[k]; pt.E[k] = E;
      pt.woffoff[k] = rowbase[k]; pt.ndst[k] = nd; pt.mode[k] = small;
      pt.bstart[k] = pb;
      pb += small ? imin(128, (E + 256*PCHUNK - 1)/(256*PCHUNK)) : (E + 255)/256;
    }
    ht.bstart[8] = hb; pt.bstart[8] = pb;
    hist_all<<<hb, 256, 0, stream>>>(ht, (int*)(wsf + o_cnt));
    scan1<<<SCAN_NB, 256, 0, stream>>>((int*)(wsf + o_cnt), rpb_p, (int*)(wsf + o_bsum));
    scan2<<<1, 512, 0, stream>>>((int*)(wsf + o_bsum));
    scan3<<<(SCAN_N + 255)/256, 256, 0, stream>>>(rpb_p, (int*)(wsf + o_woff),
                                                  (int*)(wsf + o_bsum));
    place_all<<<pb, 256, 0, stream>>>(pt, (int*)(wsf + o_woff), csr_p);
  }

  // ---------------- encoders (merged)
  {
    EncTab et2;
    et2.cum[0] = 0;
    et2.cum[1] = A_N*128;
    et2.cum[2] = et2.cum[1] + C_N*128;
    et2.cum[3] = et2.cum[2] + G_N*128;
    et2.cum[4] = et2.cum[3] + 307200;
    et2.xoff[0] = coff[0]; et2.woff[0] = coff[4];  et2.boff[0] = coff[5];
    et2.zoff[0] = u_big0;  et2.K[0] = 7;
    et2.xoff[1] = coff[1]; et2.woff[1] = coff[8];  et2.boff[1] = coff[9];
    et2.zoff[1] = u_zC;    et2.K[1] = 3;
    et2.xoff[2] = coff[3]; et2.woff[2] = coff[16]; et2.boff[2] = coff[17];
    et2.zoff[2] = u_zG;    et2.K[2] = 2;
    et2.xoff[3] = coff[2]; et2.woff[3] = 0; et2.boff[3] = 0;
    et2.zoff[3] = u_xEb;   et2.K[3] = 0;
    enc_batch<<<(et2.cum[4] + 255)/256, 256, 0, stream>>>(wsf, wsu, et2);
  }

  auto pushG = [&](GB2Tab& T, GB2 g){
    T.d[T.n] = g;
    T.b0[T.n + 1] = T.b0[T.n] + (g.M + 63)/64;
    T.n++;
  };

  // gemmA: country l2, event l1, games l2, athlete l2
  {
    GB2Tab t; t.n = 0; t.b0[0] = 0;
    pushG(t, GB2{u_zC, 128, 0,0,1000, u_eCW2, 4, coff[11], u_sxC, 256, C_N, 0, 0});
    pushG(t, GB2{u_xEb, 384, 0,0,1000, u_eEW1, 12, coff[13], u_zE, 128, V_N, FLAG_RELU, 0});
    pushG(t, GB2{u_zG, 128, 0,0,1000, u_eGW2, 4, coff[19], u_sxG, 384, G_N, 0, 0});
    pushG(t, GB2{u_big0, 128, 0,0,1000, u_eAW2, 4, coff[7], u_bigH, 128, A_N, 0, 0});
    mfma_gemm_b2<<<t.b0[t.n], 256, 0, stream>>>(d_ws, t);
  }
  // gemmB: event l2
  {
    GB2Tab t; t.n = 0; t.b0[0] = 0;
    pushG(t, GB2{u_zE, 128, 0,0,1000, u_eEW2, 4, coff[15], u_sxE, 384, V_N, 0, 0});
    mfma_gemm_b2<<<t.b0[t.n], 256, 0, stream>>>(d_ws, t);
  }

  // ---------------- SAGE layer
  hipMemsetAsync(wsf + o_aggS, 0, (size_t)1950*128*4, stream);
  const int b0 = o_aggS, b2 = o_aggS + 230*128, b7 = b2 + 800*128,
            b4 = b7 + 800*128, b6 = b4 + 60*128;
  SgTab sg;
  sg.d[0] = SgD{u_bigH, 128, rowbase[0], b0, C_N, 32};
  sg.d[1] = SgD{u_bigH, 128, rowbase[2], b2, V_N, 16};
  sg.d[2] = SgD{u_sxG, 384, rowbase[7], b7, V_N, 8};
  sg.d[3] = SgD{u_bigH, 128, rowbase[4], b4, G_N, 128};
  sg.d[4] = SgD{u_sxE, 384, rowbase[6], b6, G_N, 32};
  sg.cumw[0] = 0;
  {
    int c = 0;
    for (int i = 0; i < 5; ++i){ c += sg.d[i].nd*sg.d[i].nc; sg.cumw[i+1] = c; }
  }
  sage_small<<<(sg.cumw[5]*64 + 255)/256, 256, 0, stream>>>(wsu, wsf, csr_p, rpb_p, sg);
  AfTab af; af.n = 5;
  af.d[0] = AfD{b0, rowbase[0], u_sxC + 128, 256, C_N};
  af.d[1] = AfD{b2, rowbase[2], u_sxE + 128, 384, V_N};
  af.d[2] = AfD{b7, rowbase[7], u_sxE + 256, 384, V_N};
  af.d[3] = AfD{b4, rowbase[4], u_sxG + 128, 384, G_N};
  af.d[4] = AfD{b6, rowbase[6], u_sxG + 256, 384, G_N};
  int aftot = 1950*128;
  aggfin_batch<<<(aftot + 255)/256, 256, 0, stream>>>(wsu, wsf, rpb_p, af, aftot);

  // gemmC: SAGE linears (C/E/G)
  {
    GB2Tab t; t.n = 0; t.b0[0] = 0;
    pushG(t, GB2{u_sxC, 256, 0,0,1000, u_sxCW, 8,  o_sbcomb + 128, u_yC, 128, C_N, FLAG_RELU, 0});
    pushG(t, GB2{u_sxE, 384, 0,0,1000, u_sxEW, 12, o_sbcomb + 256, u_yE, 128, V_N, FLAG_RELU, 0});
    pushG(t, GB2{u_sxG, 384, 0,0,1000, u_sxGW, 12, o_sbcomb + 384, u_yG, 128, G_N, FLAG_RELU, 0});
    mfma_gemm_b2<<<t.b0[t.n], 256, 0, stream>>>(d_ws, t);
  }
  // SAGE athlete fused: gather + K=512 GEMM -> yA (u_big0)
  sage_ath_fused<<<(A_N + 63)/64, 256, 0, stream>>>(wsu, wsf, csr_p, rpb_p,
      u_sxC, u_sxE, u_sxG, rowbase[1], rowbase[3], rowbase[5],
      u_bigH, u_sxAW, o_sbcomb, u_big0);

  // ---------------- GAT layer
  // gemmD: gxl (3 col-groups) + 10 small frag GEMMs
  {
    GB2Tab t; t.n = 0; t.b0[0] = 0;
    pushG(t, GB2{u_big0, 128, 0,0,1000, u_gxlW, 4, o_gblx, u_bigA, 384, A_N, 0, 0});
    pushG(t, GB2{u_big0, 128, 0,0,1000, u_gxlW, 4, o_gblx, u_bigA, 384, A_N, 0, 1});
    pushG(t, GB2{u_big0, 128, 0,0,1000, u_gxlW, 4, o_gblx, u_bigA, 384, A_N, 0, 2});
    pushG(t, GB2{u_yC, 128, 0,0,1000, u_smW[0], 4, o_gbl + 1*128, u_xl1, 128, C_N, 0, 0});
    pushG(t, GB2{u_yE, 128, 0,0,1000, u_smW[1], 4, o_gbl + 3*128, u_xl3, 128, V_N, 0, 0});
    pushG(t, GB2{u_yG, 128, 0,0,1000, u_smW[2], 4, o_gbl + 5*128, u_xl5, 128, G_N, 0, 0});
    pushG(t, GB2{u_yE, 128, 0,0,1000, u_smW[3], 4, o_gbl + 6*128, u_xl6, 128, V_N, 0, 0});
    pushG(t, GB2{u_yG, 128, 0,0,1000, u_smW[4], 4, o_gbl + 7*128, u_xl7, 128, G_N, 0, 0});
    pushG(t, GB2{u_yC, 128, 0,0,1000, u_smW[5], 4, o_gbr + 0*128, u_xr0, 128, C_N, 0, 0});
    pushG(t, GB2{u_yE, 128, 0,0,1000, u_smW[6], 4, o_gbr + 2*128, u_xr2, 128, V_N, 0, 0});
    pushG(t, GB2{u_yG, 128, 0,0,1000, u_smW[7], 4, o_gbr + 4*128, u_xr4, 128, G_N, 0, 0});
    pushG(t, GB2{u_yG, 128, 0,0,1000, u_smW[8], 4, o_gbr + 6*128, u_xr6, 128, G_N, 0, 0});
    pushG(t, GB2{u_yE, 128, 0,0,1000, u_smW[9], 4, o_gbr + 7*128, u_xr7, 128, V_N, 0, 0});
    mfma_gemm_b2<<<t.b0[t.n], 256, 0, stream>>>(d_ws, t);
  }

  GoTab go;
  go.d[0] = GoD{u_bigA + 0,   384, u_xr0, o_gatt + 0*128, rowbase[0], 0,     C_N, 32};
  go.d[1] = GoD{u_bigA + 128, 384, u_xr2, o_gatt + 2*128, rowbase[2], 7360,  V_N, 16};
  go.d[2] = GoD{u_bigA + 256, 384, u_xr4, o_gatt + 4*128, rowbase[4], 20160, G_N, 128};
  go.d[3] = GoD{u_xl6, 128,        u_xr6, o_gatt + 6*128, rowbase[6], 27840, G_N, 32};
  go.d[4] = GoD{u_xl7, 128,        u_xr7, o_gatt + 7*128, rowbase[7], 29760, V_N, 8};
  go.cumw[0] = 0;
  {
    int c = 0;
    for (int i = 0; i < 5; ++i){ c += go.d[i].nd*go.d[i].nc; go.cumw[i+1] = c; }
  }
  gat_online_batch<<<(go.cumw[5]*64 + 255)/256, 256, 0, stream>>>(wsu, wsf, csr_p, rpb_p,
      wsf + o_part, go);

  // GAT athlete fused: gxr GEMM (LDS) + attention -> outA (u_bigH)
  gat_ath_fused<<<(A_N + 63)/64, 256, 0, stream>>>(wsu, wsf, csr_p, rpb_p,
      u_big0, u_gxrW, o_gbrx, u_xl1, u_xl3, u_xl5, o_gatt,
      rowbase[1], rowbase[3], rowbase[5], u_bigH);

  MgTab mg;
  mg.d[0] = MgD{0,     o_outC0, C_N, 32,  1.0f};
  mg.d[1] = MgD{7360,  o_outE2, V_N, 16,  0.5f};
  mg.d[2] = MgD{20160, o_outG4, G_N, 128, 0.5f};
  mg.d[3] = MgD{27840, o_outG6, G_N, 32,  0.5f};
  mg.d[4] = MgD{29760, o_outE7, V_N, 8,   0.5f};
  mg.cumw[0] = 0;
  {
    int c = 0;
    for (int i = 0; i < 5; ++i){ c += mg.d[i].nd; mg.cumw[i+1] = c; }
  }
  gat_merge_batch<<<(mg.cumw[5]*64 + 255)/256, 256, 0, stream>>>(wsf + o_part, wsf, mg);

  final_out<<<(101090*128 + 255)/256, 256, 0, stream>>>(wsu, wsf, u_bigH,
      o_outC0, o_outE2, o_outE7, o_outG4, o_outG6, o_gbcomb, flagp, d_out);
}